// Round 1
// baseline (14911.398 us; speedup 1.0000x reference)
//
#include <hip/hip_runtime.h>
#include <math.h>

#define DEV_INLINE __device__ __forceinline__

DEV_INLINE float lrelu(float x){ return x > 0.f ? x : 0.2f*x; }
// monotone float->uint mapping for atomicMax on floats
DEV_INLINE unsigned fmap(float f){ unsigned u=__float_as_uint(f); return (u&0x80000000u)? ~u : (u|0x80000000u); }
DEV_INLINE float funmap(unsigned u){ return __uint_as_float((u&0x80000000u)? (u^0x80000000u) : ~u); }
DEV_INLINE float eluf(float x){ return x>0.f? x : (__expf(x)-1.f); }
DEV_INLINE float bcast(float v, int l){
  return __uint_as_float((unsigned)__builtin_amdgcn_readlane((int)__float_as_uint(v), l));
}

// ---------------- node GEMM: C[n][64] = A[n][K] @ W[K][64] (+bias) ----------------
__global__ __launch_bounds__(256) void gemm_n64(const float* __restrict__ A, const float* __restrict__ W,
    const float* __restrict__ bias, float* __restrict__ C, int n, int K)
{
  int j = threadIdx.x & 63;
  int node = blockIdx.x*4 + (threadIdx.x>>6);
  if (node >= n) return;
  const float4* A4 = (const float4*)(A + (size_t)node*K);
  float acc = 0.f;
  int K4 = K>>2;
  for (int k4 = 0; k4 < K4; ++k4) {
    float4 a = A4[k4];
    const float* w = W + k4*256 + j;
    acc = fmaf(a.x, w[0],   acc);
    acc = fmaf(a.y, w[64],  acc);
    acc = fmaf(a.z, w[128], acc);
    acc = fmaf(a.w, w[192], acc);
  }
  if (bias) acc += bias[j];
  C[(size_t)node*64 + j] = acc;
}

// ---------------- layer 1 (8 heads x 8 feats) ----------------
// thread per (node, head): al_src/al_dst dots, init m with self-loop e, den=0
__global__ __launch_bounds__(256) void al_init1(const float* __restrict__ xW, const float* __restrict__ a_src,
    const float* __restrict__ a_dst, float* __restrict__ alS, float* __restrict__ alD,
    unsigned* __restrict__ m, float* __restrict__ den, int n)
{
  int t = blockIdx.x*blockDim.x + threadIdx.x;
  if (t >= n*8) return;
  int h = t & 7;
  const float4* xw4 = (const float4*)(xW + (size_t)(t>>3)*64 + h*8);
  float4 x0 = xw4[0], x1 = xw4[1];
  const float4* as4 = (const float4*)(a_src + h*8);
  const float4* ad4 = (const float4*)(a_dst + h*8);
  float4 s0 = as4[0], s1 = as4[1], d0 = ad4[0], d1 = ad4[1];
  float s = x0.x*s0.x + x0.y*s0.y + x0.z*s0.z + x0.w*s0.w
          + x1.x*s1.x + x1.y*s1.y + x1.z*s1.z + x1.w*s1.w;
  float d = x0.x*d0.x + x0.y*d0.y + x0.z*d0.z + x0.w*d0.w
          + x1.x*d1.x + x1.y*d1.y + x1.z*d1.z + x1.w*d1.w;
  alS[t] = s; alD[t] = d;
  m[t] = fmap(lrelu(s + d));   // self-loop seeds the max
  den[t] = 0.f;
}

__global__ __launch_bounds__(256) void edge_max1(const int* __restrict__ src, const int* __restrict__ dst,
    const float* __restrict__ alS, const float* __restrict__ alD, unsigned* __restrict__ m, int E)
{
  int e = blockIdx.x*blockDim.x + threadIdx.x;
  if (e >= E) return;
  int s = src[e], d = dst[e];
  const float4* as4 = (const float4*)(alS + (size_t)s*8);
  const float4* ad4 = (const float4*)(alD + (size_t)d*8);
  float4 a0 = as4[0], a1 = as4[1], b0 = ad4[0], b1 = ad4[1];
  unsigned* md = m + (size_t)d*8;
  atomicMax(md+0, fmap(lrelu(a0.x+b0.x)));
  atomicMax(md+1, fmap(lrelu(a0.y+b0.y)));
  atomicMax(md+2, fmap(lrelu(a0.z+b0.z)));
  atomicMax(md+3, fmap(lrelu(a0.w+b0.w)));
  atomicMax(md+4, fmap(lrelu(a1.x+b1.x)));
  atomicMax(md+5, fmap(lrelu(a1.y+b1.y)));
  atomicMax(md+6, fmap(lrelu(a1.z+b1.z)));
  atomicMax(md+7, fmap(lrelu(a1.w+b1.w)));
}

__global__ __launch_bounds__(256) void edge_acc1(const int* __restrict__ src, const int* __restrict__ dst,
    const float* __restrict__ alS, const float* __restrict__ alD, const unsigned* __restrict__ m,
    const float* __restrict__ xW, float* __restrict__ den, float* __restrict__ acc, int E)
{
  int e = blockIdx.x*blockDim.x + threadIdx.x;
  if (e >= E) return;
  int s = src[e], d = dst[e];
  const float4* as4 = (const float4*)(alS + (size_t)s*8);
  const float4* ad4 = (const float4*)(alD + (size_t)d*8);
  float4 a0 = as4[0], a1 = as4[1], b0 = ad4[0], b1 = ad4[1];
  const uint4* m4 = (const uint4*)(m + (size_t)d*8);
  uint4 m0 = m4[0], m1 = m4[1];
  float w[8];
  w[0] = __expf(lrelu(a0.x+b0.x) - funmap(m0.x));
  w[1] = __expf(lrelu(a0.y+b0.y) - funmap(m0.y));
  w[2] = __expf(lrelu(a0.z+b0.z) - funmap(m0.z));
  w[3] = __expf(lrelu(a0.w+b0.w) - funmap(m0.w));
  w[4] = __expf(lrelu(a1.x+b1.x) - funmap(m1.x));
  w[5] = __expf(lrelu(a1.y+b1.y) - funmap(m1.y));
  w[6] = __expf(lrelu(a1.z+b1.z) - funmap(m1.z));
  w[7] = __expf(lrelu(a1.w+b1.w) - funmap(m1.w));
  float* dd = den + (size_t)d*8;
  #pragma unroll
  for (int h = 0; h < 8; ++h) atomicAdd(dd+h, w[h]);
  const float4* xw4 = (const float4*)(xW + (size_t)s*64);
  float* ad = acc + (size_t)d*64;
  #pragma unroll
  for (int q = 0; q < 16; ++q) {
    float4 v = xw4[q];
    float wh = w[q>>1];
    float* b = ad + q*4;
    atomicAdd(b+0, wh*v.x);
    atomicAdd(b+1, wh*v.y);
    atomicAdd(b+2, wh*v.z);
    atomicAdd(b+3, wh*v.w);
  }
}

// thread per (node, l): add self-loop term, divide, +bias, ELU (in-place on acc)
__global__ __launch_bounds__(256) void fin1(const float* __restrict__ xW, const float* __restrict__ alS,
    const float* __restrict__ alD, const unsigned* __restrict__ m, const float* __restrict__ den,
    const float* __restrict__ b, float* __restrict__ acc, int n)
{
  int t = blockIdx.x*blockDim.x + threadIdx.x;
  if (t >= n*64) return;
  int l = t & 63, node = t >> 6, h = l >> 3;
  float mv = funmap(m[(size_t)node*8 + h]);
  float eself = lrelu(alS[(size_t)node*8 + h] + alD[(size_t)node*8 + h]);
  float w = __expf(eself - mv);
  float dtot = den[(size_t)node*8 + h] + w + 1e-16f;
  float v = (acc[t] + w * xW[t]) / dtot + b[l];
  acc[t] = eluf(v);
}

// ---------------- layer 2 (1 head x 64 feats) ----------------
__global__ __launch_bounds__(256) void al_init2(const float* __restrict__ xW, const float* __restrict__ a_src,
    const float* __restrict__ a_dst, float* __restrict__ alS, float* __restrict__ alD,
    unsigned* __restrict__ m, float* __restrict__ den, int n)
{
  int node = blockIdx.x*blockDim.x + threadIdx.x;
  if (node >= n) return;
  const float4* xw4 = (const float4*)(xW + (size_t)node*64);
  const float4* as4 = (const float4*)a_src;
  const float4* ad4 = (const float4*)a_dst;
  float s = 0.f, d = 0.f;
  #pragma unroll
  for (int q = 0; q < 16; ++q) {
    float4 v = xw4[q], a = as4[q], bb = ad4[q];
    s += v.x*a.x + v.y*a.y + v.z*a.z + v.w*a.w;
    d += v.x*bb.x + v.y*bb.y + v.z*bb.z + v.w*bb.w;
  }
  alS[node] = s; alD[node] = d;
  m[node] = fmap(lrelu(s + d));
  den[node] = 0.f;
}

__global__ __launch_bounds__(256) void edge_max2(const int* __restrict__ src, const int* __restrict__ dst,
    const float* __restrict__ alS, const float* __restrict__ alD, unsigned* __restrict__ m, int E)
{
  int e = blockIdx.x*blockDim.x + threadIdx.x;
  if (e >= E) return;
  int s = src[e], d = dst[e];
  atomicMax(m + d, fmap(lrelu(alS[s] + alD[d])));
}

__global__ __launch_bounds__(256) void edge_acc2(const int* __restrict__ src, const int* __restrict__ dst,
    const float* __restrict__ alS, const float* __restrict__ alD, const unsigned* __restrict__ m,
    const float* __restrict__ xW, float* __restrict__ den, float* __restrict__ acc, int E)
{
  int e = blockIdx.x*blockDim.x + threadIdx.x;
  if (e >= E) return;
  int s = src[e], d = dst[e];
  float w = __expf(lrelu(alS[s] + alD[d]) - funmap(m[d]));
  atomicAdd(den + d, w);
  const float4* xw4 = (const float4*)(xW + (size_t)s*64);
  float* ad = acc + (size_t)d*64;
  #pragma unroll
  for (int q = 0; q < 16; ++q) {
    float4 v = xw4[q];
    float* b = ad + q*4;
    atomicAdd(b+0, w*v.x);
    atomicAdd(b+1, w*v.y);
    atomicAdd(b+2, w*v.z);
    atomicAdd(b+3, w*v.w);
  }
}

__global__ __launch_bounds__(256) void fin2(const float* __restrict__ xW, const float* __restrict__ alS,
    const float* __restrict__ alD, const unsigned* __restrict__ m, const float* __restrict__ den,
    const float* __restrict__ b, float* __restrict__ acc, int n)
{
  int t = blockIdx.x*blockDim.x + threadIdx.x;
  if (t >= n*64) return;
  int l = t & 63, node = t >> 6;
  float mv = funmap(m[node]);
  float eself = lrelu(alS[node] + alD[node]);
  float w = __expf(eself - mv);
  float dtot = den[node] + w + 1e-16f;
  float v = (acc[t] + w * xW[t]) / dtot + b[l];
  acc[t] = eluf(v);
}

// ---------------- edge MLP: wave per edge, hidden split in halves of 64 ----------------
__global__ __launch_bounds__(256) void edge_mlp_phase(const float* __restrict__ h3, const int* __restrict__ src,
    const int* __restrict__ dst, const float* __restrict__ attr, const float* __restrict__ W1,
    const float* __restrict__ b1, const float* __restrict__ W2, float* __restrict__ part, int E)
{
  const int half = blockIdx.y;
  __shared__ float W1s[144*64];   // 36,864 B
  for (int i = threadIdx.x; i < 144*64; i += 256)
    W1s[i] = W1[(i>>6)*128 + half*64 + (i&63)];
  __syncthreads();

  const int lane = threadIdx.x & 63;
  const int wid  = (blockIdx.x*blockDim.x + threadIdx.x) >> 6;
  const int nw   = (gridDim.x*blockDim.x) >> 6;
  const float bias = b1[half*64 + lane];
  const float w2a = W2[(half*64 + lane)*2 + 0];
  const float w2b = W2[(half*64 + lane)*2 + 1];

  for (int e = wid; e < E; e += nw) {
    int s = src[e], d = dst[e];
    float efs = h3[(size_t)s*64 + lane];
    float efd = h3[(size_t)d*64 + lane];
    float efa = (lane < 16) ? attr[(size_t)e*16 + lane] : 0.f;
    float acc = bias;
    #pragma unroll
    for (int r = 0; r < 64; ++r) acc = fmaf(bcast(efs, r), W1s[r*64 + lane], acc);
    #pragma unroll
    for (int r = 0; r < 64; ++r) acc = fmaf(bcast(efd, r), W1s[(64+r)*64 + lane], acc);
    #pragma unroll
    for (int r = 0; r < 16; ++r) acc = fmaf(bcast(efa, r), W1s[(128+r)*64 + lane], acc);
    float hv = fmaxf(acc, 0.f);
    float p0 = hv * w2a, p1 = hv * w2b;
    #pragma unroll
    for (int o = 32; o > 0; o >>= 1) { p0 += __shfl_xor(p0, o, 64); p1 += __shfl_xor(p1, o, 64); }
    if (lane == 0)
      ((float2*)part)[(size_t)e*2 + half] = make_float2(p0, p1);
  }
}

__global__ __launch_bounds__(256) void mlp_final(const float* __restrict__ part, const float* __restrict__ b2,
    float* __restrict__ out, int E)
{
  int e = blockIdx.x*blockDim.x + threadIdx.x;
  if (e >= E) return;
  float4 p = ((const float4*)part)[e];     // [p0_h0, p1_h0, p0_h1, p1_h1]
  float p0 = p.x + p.z + b2[0];
  float p1 = p.y + p.w + b2[1];
  float mm = fmaxf(p0, p1);
  float ls = mm + logf(__expf(p0-mm) + __expf(p1-mm));
  out[(size_t)e*2 + 0] = p0 - ls;
  out[(size_t)e*2 + 1] = p1 - ls;
}

extern "C" void kernel_launch(void* const* d_in, const int* in_sizes, int n_in,
                              void* d_out, int out_size, void* d_ws, size_t ws_size,
                              hipStream_t stream) {
  const float* x      = (const float*)d_in[0];
  const int*   ei     = (const int*)d_in[1];
  const float* attr   = (const float*)d_in[2];
  const float* W1     = (const float*)d_in[3];
  const float* a_src1 = (const float*)d_in[4];
  const float* a_dst1 = (const float*)d_in[5];
  const float* b1     = (const float*)d_in[6];
  const float* W2     = (const float*)d_in[7];
  const float* a_src2 = (const float*)d_in[8];
  const float* a_dst2 = (const float*)d_in[9];
  const float* b2     = (const float*)d_in[10];
  const float* linW   = (const float*)d_in[11];
  const float* linb   = (const float*)d_in[12];
  const float* mW1    = (const float*)d_in[13];
  const float* mb1    = (const float*)d_in[14];
  const float* mW2    = (const float*)d_in[15];
  const float* mb2    = (const float*)d_in[16];
  float* out = (float*)d_out;

  int N = in_sizes[0] / 128;
  int E = in_sizes[1] / 2;
  const int* src = ei;
  const int* dst = ei + E;

  char* ws = (char*)d_ws;
  float*    bufA = (float*)(ws);                 // 25.6 MB: xW1 / xW2 / h3
  float*    bufH = (float*)(ws + 25600000);      // 25.6 MB: acc1/h1, acc2/h2, then MLP partials
  float*    alS1 = (float*)(ws + 51200000);
  float*    alD1 = (float*)(ws + 54400000);
  unsigned* m1   = (unsigned*)(ws + 57600000);
  float*    den1 = (float*)(ws + 60800000);
  float*    alS2 = (float*)(ws + 64000000);
  float*    alD2 = (float*)(ws + 64400000);
  unsigned* m2   = (unsigned*)(ws + 64800000);
  float*    den2 = (float*)(ws + 65200000);
  float*    part = bufH;

  int gN4   = (N + 3) / 4;
  int gNH   = (N*8 + 255) / 256;
  int gN    = (N + 255) / 256;
  int gNL   = (N*64 + 255) / 256;
  int gE    = (E + 255) / 256;

  // layer 1
  hipMemsetAsync(bufH, 0, (size_t)N*64*sizeof(float), stream);
  gemm_n64<<<gN4, 256, 0, stream>>>(x, W1, nullptr, bufA, N, 128);
  al_init1<<<gNH, 256, 0, stream>>>(bufA, a_src1, a_dst1, alS1, alD1, m1, den1, N);
  edge_max1<<<gE, 256, 0, stream>>>(src, dst, alS1, alD1, m1, E);
  edge_acc1<<<gE, 256, 0, stream>>>(src, dst, alS1, alD1, m1, bufA, den1, bufH, E);
  fin1<<<gNL, 256, 0, stream>>>(bufA, alS1, alD1, m1, den1, b1, bufH, N);
  // layer 2
  gemm_n64<<<gN4, 256, 0, stream>>>(bufH, W2, nullptr, bufA, N, 64);
  al_init2<<<gN, 256, 0, stream>>>(bufA, a_src2, a_dst2, alS2, alD2, m2, den2, N);
  hipMemsetAsync(bufH, 0, (size_t)N*64*sizeof(float), stream);
  edge_max2<<<gE, 256, 0, stream>>>(src, dst, alS2, alD2, m2, E);
  edge_acc2<<<gE, 256, 0, stream>>>(src, dst, alS2, alD2, m2, bufA, den2, bufH, E);
  fin2<<<gNL, 256, 0, stream>>>(bufA, alS2, alD2, m2, den2, b2, bufH, N);
  // linear
  gemm_n64<<<gN4, 256, 0, stream>>>(bufH, linW, linb, bufA, N, 64);
  // edge MLP (h3 = bufA; partials overwrite bufH which is now dead)
  dim3 gMLP(1024, 2);
  edge_mlp_phase<<<gMLP, 256, 0, stream>>>(bufA, src, dst, attr, mW1, mb1, mW2, part, E);
  mlp_final<<<gE, 256, 0, stream>>>(part, mb2, out, E);
}

// Round 2
// 3428.815 us; speedup vs baseline: 4.3488x; 4.3488x over previous
//
#include <hip/hip_runtime.h>
#include <math.h>

#define DEV_INLINE __device__ __forceinline__

DEV_INLINE float lrelu(float x){ return x > 0.f ? x : 0.2f*x; }
DEV_INLINE float eluf(float x){ return x>0.f? x : (__expf(x)-1.f); }
DEV_INLINE float bcast(float v, int l){
  return __uint_as_float((unsigned)__builtin_amdgcn_readlane((int)__float_as_uint(v), l));
}

// ---------------- node GEMM: C[n][64] = A[n][K] @ W[K][64] (+bias) ----------------
__global__ __launch_bounds__(256) void gemm_n64(const float* __restrict__ A, const float* __restrict__ W,
    const float* __restrict__ bias, float* __restrict__ C, int n, int K)
{
  int j = threadIdx.x & 63;
  int node = blockIdx.x*4 + (threadIdx.x>>6);
  if (node >= n) return;
  const float4* A4 = (const float4*)(A + (size_t)node*K);
  float acc = 0.f;
  int K4 = K>>2;
  for (int k4 = 0; k4 < K4; ++k4) {
    float4 a = A4[k4];
    const float* w = W + k4*256 + j;
    acc = fmaf(a.x, w[0],   acc);
    acc = fmaf(a.y, w[64],  acc);
    acc = fmaf(a.z, w[128], acc);
    acc = fmaf(a.w, w[192], acc);
  }
  if (bias) acc += bias[j];
  C[(size_t)node*64 + j] = acc;
}

// ---------------- CSR build (grouped by dst) ----------------
__global__ __launch_bounds__(256) void hist_kernel(const int* __restrict__ dst, int* __restrict__ deg, int E)
{
  int e = blockIdx.x*blockDim.x + threadIdx.x;
  if (e < E) atomicAdd(deg + dst[e], 1);
}

// chunk = 1024 elements per block
__global__ __launch_bounds__(256) void scan_p1(const int* __restrict__ deg, int* __restrict__ part, int n)
{
  __shared__ int red[256];
  int base = blockIdx.x*1024;
  int s = 0;
  for (int k = threadIdx.x; k < 1024; k += 256) { int i = base+k; s += (i<n)? deg[i] : 0; }
  red[threadIdx.x] = s; __syncthreads();
  for (int off = 128; off > 0; off >>= 1) {
    if (threadIdx.x < off) red[threadIdx.x] += red[threadIdx.x+off];
    __syncthreads();
  }
  if (threadIdx.x == 0) part[blockIdx.x] = red[0];
}

__global__ void scan_p2(int* part, int* rowptr, int nb, int n)
{
  if (threadIdx.x == 0 && blockIdx.x == 0) {
    int run = 0;
    for (int b = 0; b < nb; ++b) { int v = part[b]; part[b] = run; run += v; }
    rowptr[n] = run;
  }
}

__global__ __launch_bounds__(256) void scan_p3(const int* __restrict__ deg, const int* __restrict__ part,
    int* __restrict__ rowptr, int n)
{
  __shared__ int ts[256];
  int tid = threadIdx.x;
  int base = blockIdx.x*1024 + tid*4;
  int v0=0,v1=0,v2=0,v3=0;
  if (base+0 < n) v0 = deg[base+0];
  if (base+1 < n) v1 = deg[base+1];
  if (base+2 < n) v2 = deg[base+2];
  if (base+3 < n) v3 = deg[base+3];
  ts[tid] = v0+v1+v2+v3; __syncthreads();
  for (int off = 1; off < 256; off <<= 1) {
    int t = (tid >= off) ? ts[tid-off] : 0;
    __syncthreads();
    ts[tid] += t;
    __syncthreads();
  }
  int ex = part[blockIdx.x] + (tid ? ts[tid-1] : 0);
  if (base+0 < n) { rowptr[base+0] = ex; ex += v0; }
  if (base+1 < n) { rowptr[base+1] = ex; ex += v1; }
  if (base+2 < n) { rowptr[base+2] = ex; ex += v2; }
  if (base+3 < n) { rowptr[base+3] = ex; ex += v3; }
}

__global__ __launch_bounds__(256) void copy_int(const int* __restrict__ a, int* __restrict__ b, int n)
{
  int i = blockIdx.x*blockDim.x + threadIdx.x;
  if (i < n) b[i] = a[i];
}

__global__ __launch_bounds__(256) void scatter_kernel(const int* __restrict__ src, const int* __restrict__ dst,
    int* __restrict__ cursor, int* __restrict__ csr, int E)
{
  int e = blockIdx.x*blockDim.x + threadIdx.x;
  if (e >= E) return;
  int pos = atomicAdd(cursor + dst[e], 1);
  csr[pos] = src[e];
}

// ---------------- attention-logit precompute ----------------
__global__ __launch_bounds__(256) void al_init1(const float* __restrict__ xW, const float* __restrict__ a_src,
    const float* __restrict__ a_dst, float* __restrict__ alS, float* __restrict__ alD, int n)
{
  int t = blockIdx.x*blockDim.x + threadIdx.x;
  if (t >= n*8) return;
  int h = t & 7;
  const float4* xw4 = (const float4*)(xW + (size_t)(t>>3)*64 + h*8);
  float4 x0 = xw4[0], x1 = xw4[1];
  const float4* as4 = (const float4*)(a_src + h*8);
  const float4* ad4 = (const float4*)(a_dst + h*8);
  float4 s0 = as4[0], s1 = as4[1], d0 = ad4[0], d1 = ad4[1];
  alS[t] = x0.x*s0.x + x0.y*s0.y + x0.z*s0.z + x0.w*s0.w
         + x1.x*s1.x + x1.y*s1.y + x1.z*s1.z + x1.w*s1.w;
  alD[t] = x0.x*d0.x + x0.y*d0.y + x0.z*d0.z + x0.w*d0.w
         + x1.x*d1.x + x1.y*d1.y + x1.z*d1.z + x1.w*d1.w;
}

__global__ __launch_bounds__(256) void al_init2(const float* __restrict__ xW, const float* __restrict__ a_src,
    const float* __restrict__ a_dst, float* __restrict__ alS, float* __restrict__ alD, int n)
{
  int node = blockIdx.x*blockDim.x + threadIdx.x;
  if (node >= n) return;
  const float4* xw4 = (const float4*)(xW + (size_t)node*64);
  const float4* as4 = (const float4*)a_src;
  const float4* ad4 = (const float4*)a_dst;
  float s = 0.f, d = 0.f;
  #pragma unroll
  for (int q = 0; q < 16; ++q) {
    float4 v = xw4[q], a = as4[q], bb = ad4[q];
    s += v.x*a.x + v.y*a.y + v.z*a.z + v.w*a.w;
    d += v.x*bb.x + v.y*bb.y + v.z*bb.z + v.w*bb.w;
  }
  alS[node] = s; alD[node] = d;
}

// ---------------- per-node gather + online softmax aggregation ----------------
// Layer 1: 8 heads x 8 feats. Wave per node, lane = output channel, h = lane>>3.
__global__ __launch_bounds__(256) void agg1(const float* __restrict__ xW, const float* __restrict__ alS,
    const float* __restrict__ alD, const int* __restrict__ rowptr, const int* __restrict__ csr,
    const float* __restrict__ b, float* __restrict__ outp, int n)
{
  int node = blockIdx.x*4 + (threadIdx.x>>6);
  if (node >= n) return;
  int l = threadIdx.x & 63, h = l >> 3;
  float aD  = alD[(size_t)node*8 + h];
  float m   = lrelu(alS[(size_t)node*8 + h] + aD);  // self-loop seeds the max
  float den = 1.f;                                   // exp(self - self) = 1
  float acc = xW[(size_t)node*64 + l];
  int p0 = rowptr[node], p1 = rowptr[node+1];
  for (int p = p0; p < p1; ++p) {
    int s = csr[p];
    float e  = lrelu(alS[(size_t)s*8 + h] + aD);
    float xv = xW[(size_t)s*64 + l];
    float mn = fmaxf(m, e);
    float sc = __expf(m - mn);
    float w  = __expf(e - mn);
    den = den*sc + w;
    acc = acc*sc + w*xv;
    m = mn;
  }
  outp[(size_t)node*64 + l] = eluf(acc/(den + 1e-16f) + b[l]);
}

// Layer 2: 1 head x 64 feats.
__global__ __launch_bounds__(256) void agg2(const float* __restrict__ xW, const float* __restrict__ alS,
    const float* __restrict__ alD, const int* __restrict__ rowptr, const int* __restrict__ csr,
    const float* __restrict__ b, float* __restrict__ outp, int n)
{
  int node = blockIdx.x*4 + (threadIdx.x>>6);
  if (node >= n) return;
  int l = threadIdx.x & 63;
  float aD  = alD[node];
  float m   = lrelu(alS[node] + aD);
  float den = 1.f;
  float acc = xW[(size_t)node*64 + l];
  int p0 = rowptr[node], p1 = rowptr[node+1];
  for (int p = p0; p < p1; ++p) {
    int s = csr[p];
    float e  = lrelu(alS[s] + aD);
    float xv = xW[(size_t)s*64 + l];
    float mn = fmaxf(m, e);
    float sc = __expf(m - mn);
    float w  = __expf(e - mn);
    den = den*sc + w;
    acc = acc*sc + w*xv;
    m = mn;
  }
  outp[(size_t)node*64 + l] = eluf(acc/(den + 1e-16f) + b[l]);
}

// ---------------- edge MLP: wave per edge, hidden split in halves of 64 ----------------
__global__ __launch_bounds__(256) void edge_mlp_phase(const float* __restrict__ h3, const int* __restrict__ src,
    const int* __restrict__ dst, const float* __restrict__ attr, const float* __restrict__ W1,
    const float* __restrict__ b1, const float* __restrict__ W2, float* __restrict__ part, int E)
{
  const int half = blockIdx.y;
  __shared__ float W1s[144*64];   // 36,864 B
  for (int i = threadIdx.x; i < 144*64; i += 256)
    W1s[i] = W1[(i>>6)*128 + half*64 + (i&63)];
  __syncthreads();

  const int lane = threadIdx.x & 63;
  const int wid  = (blockIdx.x*blockDim.x + threadIdx.x) >> 6;
  const int nw   = (gridDim.x*blockDim.x) >> 6;
  const float bias = b1[half*64 + lane];
  const float w2a = W2[(half*64 + lane)*2 + 0];
  const float w2b = W2[(half*64 + lane)*2 + 1];

  for (int e = wid; e < E; e += nw) {
    int s = src[e], d = dst[e];
    float efs = h3[(size_t)s*64 + lane];
    float efd = h3[(size_t)d*64 + lane];
    float efa = (lane < 16) ? attr[(size_t)e*16 + lane] : 0.f;
    float acc = bias;
    #pragma unroll
    for (int r = 0; r < 64; ++r) acc = fmaf(bcast(efs, r), W1s[r*64 + lane], acc);
    #pragma unroll
    for (int r = 0; r < 64; ++r) acc = fmaf(bcast(efd, r), W1s[(64+r)*64 + lane], acc);
    #pragma unroll
    for (int r = 0; r < 16; ++r) acc = fmaf(bcast(efa, r), W1s[(128+r)*64 + lane], acc);
    float hv = fmaxf(acc, 0.f);
    float p0 = hv * w2a, p1 = hv * w2b;
    #pragma unroll
    for (int o = 32; o > 0; o >>= 1) { p0 += __shfl_xor(p0, o, 64); p1 += __shfl_xor(p1, o, 64); }
    if (lane == 0)
      ((float2*)part)[(size_t)e*2 + half] = make_float2(p0, p1);
  }
}

__global__ __launch_bounds__(256) void mlp_final(const float* __restrict__ part, const float* __restrict__ b2,
    float* __restrict__ out, int E)
{
  int e = blockIdx.x*blockDim.x + threadIdx.x;
  if (e >= E) return;
  float4 p = ((const float4*)part)[e];     // [p0_h0, p1_h0, p0_h1, p1_h1]
  float p0 = p.x + p.z + b2[0];
  float p1 = p.y + p.w + b2[1];
  float mm = fmaxf(p0, p1);
  float ls = mm + logf(__expf(p0-mm) + __expf(p1-mm));
  out[(size_t)e*2 + 0] = p0 - ls;
  out[(size_t)e*2 + 1] = p1 - ls;
}

extern "C" void kernel_launch(void* const* d_in, const int* in_sizes, int n_in,
                              void* d_out, int out_size, void* d_ws, size_t ws_size,
                              hipStream_t stream) {
  const float* x      = (const float*)d_in[0];
  const int*   ei     = (const int*)d_in[1];
  const float* attr   = (const float*)d_in[2];
  const float* W1     = (const float*)d_in[3];
  const float* a_src1 = (const float*)d_in[4];
  const float* a_dst1 = (const float*)d_in[5];
  const float* b1     = (const float*)d_in[6];
  const float* W2     = (const float*)d_in[7];
  const float* a_src2 = (const float*)d_in[8];
  const float* a_dst2 = (const float*)d_in[9];
  const float* b2     = (const float*)d_in[10];
  const float* linW   = (const float*)d_in[11];
  const float* linb   = (const float*)d_in[12];
  const float* mW1    = (const float*)d_in[13];
  const float* mb1    = (const float*)d_in[14];
  const float* mW2    = (const float*)d_in[15];
  const float* mb2    = (const float*)d_in[16];
  float* out = (float*)d_out;

  int N = in_sizes[0] / 128;
  int E = in_sizes[1] / 2;
  const int* src = ei;
  const int* dst = ei + E;

  char* ws = (char*)d_ws;
  float*    bufA   = (float*)(ws);                 // 25.6 MB: xW1 / xW2 / h3
  float*    bufH   = (float*)(ws + 25600000);      // 25.6 MB: h1 / h2 / MLP partials
  int*      csr    = (int*)  (ws + 51200000);      // 6.4 MB
  float*    alS1   = (float*)(ws + 57600000);      // 3.2 MB
  float*    alD1   = (float*)(ws + 60800000);      // 3.2 MB
  int*      rowptr = (int*)  (ws + 64000000);      // (N+1)*4
  int*      degcur = (int*)  (ws + 64400064);      // N*4 (deg, then cursor)
  int*      part   = (int*)  (ws + 64800064);      // scan partials (~400 B)
  // layer-2 logits alias dead layer-1 logit space
  float*    alS2   = (float*)(ws + 57600000);
  float*    alD2   = (float*)(ws + 58000000);
  float*    mlpP   = bufH;                         // MLP partials after h2 dead

  int gN4 = (N + 3) / 4;
  int gNH = (N*8 + 255) / 256;
  int gN  = (N + 255) / 256;
  int gE  = (E + 255) / 256;
  int nChunk = (N + 1023) / 1024;

  // ---- CSR build (per call; ws is re-poisoned every launch) ----
  hipMemsetAsync(degcur, 0, (size_t)N*sizeof(int), stream);
  hist_kernel<<<gE, 256, 0, stream>>>(dst, degcur, E);
  scan_p1<<<nChunk, 256, 0, stream>>>(degcur, part, N);
  scan_p2<<<1, 64, 0, stream>>>(part, rowptr, nChunk, N);
  scan_p3<<<nChunk, 256, 0, stream>>>(degcur, part, rowptr, N);
  copy_int<<<gN, 256, 0, stream>>>(rowptr, degcur, N);   // cursor = rowptr
  scatter_kernel<<<gE, 256, 0, stream>>>(src, dst, degcur, csr, E);

  // ---- layer 1 ----
  gemm_n64<<<gN4, 256, 0, stream>>>(x, W1, nullptr, bufA, N, 128);
  al_init1<<<gNH, 256, 0, stream>>>(bufA, a_src1, a_dst1, alS1, alD1, N);
  agg1<<<gN4, 256, 0, stream>>>(bufA, alS1, alD1, rowptr, csr, b1, bufH, N);
  // ---- layer 2 ----
  gemm_n64<<<gN4, 256, 0, stream>>>(bufH, W2, nullptr, bufA, N, 64);
  al_init2<<<gN, 256, 0, stream>>>(bufA, a_src2, a_dst2, alS2, alD2, N);
  agg2<<<gN4, 256, 0, stream>>>(bufA, alS2, alD2, rowptr, csr, b2, bufH, N);
  // ---- linear ----
  gemm_n64<<<gN4, 256, 0, stream>>>(bufH, linW, linb, bufA, N, 64);
  // ---- edge MLP ----
  dim3 gMLP(1024, 2);
  edge_mlp_phase<<<gMLP, 256, 0, stream>>>(bufA, src, dst, attr, mW1, mb1, mW2, (float*)mlpP, E);
  mlp_final<<<gE, 256, 0, stream>>>((float*)mlpP, mb2, out, E);
}

// Round 3
// 1336.211 us; speedup vs baseline: 11.1595x; 2.5661x over previous
//
#include <hip/hip_runtime.h>
#include <math.h>

#define DEV_INLINE __device__ __forceinline__
typedef unsigned short ushort;
typedef __attribute__((ext_vector_type(8))) short bf16x8;
typedef __attribute__((ext_vector_type(4))) float f32x4;

DEV_INLINE float lrelu(float x){ return x > 0.f ? x : 0.2f*x; }
DEV_INLINE float eluf(float x){ return x>0.f? x : (__expf(x)-1.f); }
DEV_INLINE ushort f2bf(float f){
  unsigned u = __float_as_uint(f);
  return (ushort)((u + 0x7FFFu + ((u>>16)&1u)) >> 16);   // RNE
}

// ---------------- node GEMM: C[n][64] = A[n][K] @ W[K][64] (+bias), optional bf16 copy ----------------
__global__ __launch_bounds__(256) void gemm_n64(const float* __restrict__ A, const float* __restrict__ W,
    const float* __restrict__ bias, float* __restrict__ C, ushort* __restrict__ Cb, int n, int K)
{
  int j = threadIdx.x & 63;
  int node = blockIdx.x*4 + (threadIdx.x>>6);
  if (node >= n) return;
  const float4* A4 = (const float4*)(A + (size_t)node*K);
  float acc = 0.f;
  int K4 = K>>2;
  for (int k4 = 0; k4 < K4; ++k4) {
    float4 a = A4[k4];
    const float* w = W + k4*256 + j;
    acc = fmaf(a.x, w[0],   acc);
    acc = fmaf(a.y, w[64],  acc);
    acc = fmaf(a.z, w[128], acc);
    acc = fmaf(a.w, w[192], acc);
  }
  if (bias) acc += bias[j];
  if (C)  C[(size_t)node*64 + j] = acc;
  if (Cb) Cb[(size_t)node*64 + j] = f2bf(acc);
}

// ---------------- CSR build (grouped by dst) ----------------
__global__ __launch_bounds__(256) void hist_kernel(const int* __restrict__ dst, int* __restrict__ deg, int E)
{
  int e = blockIdx.x*blockDim.x + threadIdx.x;
  if (e < E) atomicAdd(deg + dst[e], 1);
}

__global__ __launch_bounds__(256) void scan_p1(const int* __restrict__ deg, int* __restrict__ part, int n)
{
  __shared__ int red[256];
  int base = blockIdx.x*1024;
  int s = 0;
  for (int k = threadIdx.x; k < 1024; k += 256) { int i = base+k; s += (i<n)? deg[i] : 0; }
  red[threadIdx.x] = s; __syncthreads();
  for (int off = 128; off > 0; off >>= 1) {
    if (threadIdx.x < off) red[threadIdx.x] += red[threadIdx.x+off];
    __syncthreads();
  }
  if (threadIdx.x == 0) part[blockIdx.x] = red[0];
}

__global__ void scan_p2(int* part, int* rowptr, int nb, int n)
{
  if (threadIdx.x == 0 && blockIdx.x == 0) {
    int run = 0;
    for (int b = 0; b < nb; ++b) { int v = part[b]; part[b] = run; run += v; }
    rowptr[n] = run;
  }
}

__global__ __launch_bounds__(256) void scan_p3(const int* __restrict__ deg, const int* __restrict__ part,
    int* __restrict__ rowptr, int n)
{
  __shared__ int ts[256];
  int tid = threadIdx.x;
  int base = blockIdx.x*1024 + tid*4;
  int v0=0,v1=0,v2=0,v3=0;
  if (base+0 < n) v0 = deg[base+0];
  if (base+1 < n) v1 = deg[base+1];
  if (base+2 < n) v2 = deg[base+2];
  if (base+3 < n) v3 = deg[base+3];
  ts[tid] = v0+v1+v2+v3; __syncthreads();
  for (int off = 1; off < 256; off <<= 1) {
    int t = (tid >= off) ? ts[tid-off] : 0;
    __syncthreads();
    ts[tid] += t;
    __syncthreads();
  }
  int ex = part[blockIdx.x] + (tid ? ts[tid-1] : 0);
  if (base+0 < n) { rowptr[base+0] = ex; ex += v0; }
  if (base+1 < n) { rowptr[base+1] = ex; ex += v1; }
  if (base+2 < n) { rowptr[base+2] = ex; ex += v2; }
  if (base+3 < n) { rowptr[base+3] = ex; ex += v3; }
}

__global__ __launch_bounds__(256) void copy_int(const int* __restrict__ a, int* __restrict__ b, int n)
{
  int i = blockIdx.x*blockDim.x + threadIdx.x;
  if (i < n) b[i] = a[i];
}

__global__ __launch_bounds__(256) void scatter_kernel(const int* __restrict__ src, const int* __restrict__ dst,
    int* __restrict__ cursor, int* __restrict__ csr, int E)
{
  int e = blockIdx.x*blockDim.x + threadIdx.x;
  if (e >= E) return;
  int pos = atomicAdd(cursor + dst[e], 1);
  csr[pos] = src[e];
}

// ---------------- attention-logit precompute ----------------
__global__ __launch_bounds__(256) void al_init1(const float* __restrict__ xW, const float* __restrict__ a_src,
    const float* __restrict__ a_dst, float* __restrict__ alS, float* __restrict__ alD, int n)
{
  int t = blockIdx.x*blockDim.x + threadIdx.x;
  if (t >= n*8) return;
  int h = t & 7;
  const float4* xw4 = (const float4*)(xW + (size_t)(t>>3)*64 + h*8);
  float4 x0 = xw4[0], x1 = xw4[1];
  const float4* as4 = (const float4*)(a_src + h*8);
  const float4* ad4 = (const float4*)(a_dst + h*8);
  float4 s0 = as4[0], s1 = as4[1], d0 = ad4[0], d1 = ad4[1];
  alS[t] = x0.x*s0.x + x0.y*s0.y + x0.z*s0.z + x0.w*s0.w
         + x1.x*s1.x + x1.y*s1.y + x1.z*s1.z + x1.w*s1.w;
  alD[t] = x0.x*d0.x + x0.y*d0.y + x0.z*d0.z + x0.w*d0.w
         + x1.x*d1.x + x1.y*d1.y + x1.z*d1.z + x1.w*d1.w;
}

__global__ __launch_bounds__(256) void al_init2(const float* __restrict__ xW, const float* __restrict__ a_src,
    const float* __restrict__ a_dst, float* __restrict__ alS, float* __restrict__ alD, int n)
{
  int node = blockIdx.x*blockDim.x + threadIdx.x;
  if (node >= n) return;
  const float4* xw4 = (const float4*)(xW + (size_t)node*64);
  const float4* as4 = (const float4*)a_src;
  const float4* ad4 = (const float4*)a_dst;
  float s = 0.f, d = 0.f;
  #pragma unroll
  for (int q = 0; q < 16; ++q) {
    float4 v = xw4[q], a = as4[q], bb = ad4[q];
    s += v.x*a.x + v.y*a.y + v.z*a.z + v.w*a.w;
    d += v.x*bb.x + v.y*bb.y + v.z*bb.z + v.w*bb.w;
  }
  alS[node] = s; alD[node] = d;
}

// ---------------- per-node gather + online softmax aggregation ----------------
__global__ __launch_bounds__(256) void agg1(const float* __restrict__ xW, const float* __restrict__ alS,
    const float* __restrict__ alD, const int* __restrict__ rowptr, const int* __restrict__ csr,
    const float* __restrict__ b, float* __restrict__ outp, int n)
{
  int node = blockIdx.x*4 + (threadIdx.x>>6);
  if (node >= n) return;
  int l = threadIdx.x & 63, h = l >> 3;
  float aD  = alD[(size_t)node*8 + h];
  float m   = lrelu(alS[(size_t)node*8 + h] + aD);
  float den = 1.f;
  float acc = xW[(size_t)node*64 + l];
  int p0 = rowptr[node], p1 = rowptr[node+1];
  for (int p = p0; p < p1; ++p) {
    int s = csr[p];
    float e  = lrelu(alS[(size_t)s*8 + h] + aD);
    float xv = xW[(size_t)s*64 + l];
    float mn = fmaxf(m, e);
    float sc = __expf(m - mn);
    float w  = __expf(e - mn);
    den = den*sc + w;
    acc = acc*sc + w*xv;
    m = mn;
  }
  outp[(size_t)node*64 + l] = eluf(acc/(den + 1e-16f) + b[l]);
}

__global__ __launch_bounds__(256) void agg2(const float* __restrict__ xW, const float* __restrict__ alS,
    const float* __restrict__ alD, const int* __restrict__ rowptr, const int* __restrict__ csr,
    const float* __restrict__ b, float* __restrict__ outp, int n)
{
  int node = blockIdx.x*4 + (threadIdx.x>>6);
  if (node >= n) return;
  int l = threadIdx.x & 63;
  float aD  = alD[node];
  float m   = lrelu(alS[node] + aD);
  float den = 1.f;
  float acc = xW[(size_t)node*64 + l];
  int p0 = rowptr[node], p1 = rowptr[node+1];
  for (int p = p0; p < p1; ++p) {
    int s = csr[p];
    float e  = lrelu(alS[s] + aD);
    float xv = xW[(size_t)s*64 + l];
    float mn = fmaxf(m, e);
    float sc = __expf(m - mn);
    float w  = __expf(e - mn);
    den = den*sc + w;
    acc = acc*sc + w*xv;
    m = mn;
  }
  outp[(size_t)node*64 + l] = eluf(acc/(den + 1e-16f) + b[l]);
}

// ---------------- helper conversions for MFMA edge MLP ----------------
__global__ __launch_bounds__(256) void attr2bf(const float* __restrict__ attr, ushort* __restrict__ attrb, int n4)
{
  int t = blockIdx.x*blockDim.x + threadIdx.x;
  if (t >= n4) return;
  float4 a = ((const float4*)attr)[t];
  ushort4 o; o.x = f2bf(a.x); o.y = f2bf(a.y); o.z = f2bf(a.z); o.w = f2bf(a.w);
  ((ushort4*)attrb)[t] = o;
}

// W1[144][128] fp32 -> B-fragment-ordered bf16 image: [8 ntile][5 kstep][64 lane][8 bf16]
// frag element j of lane l: B[k = ks*32 + (l>>4)*8 + j][ncol = nt*16 + (l&15)], zero for k>=144
__global__ void w1_swizzle(const float* __restrict__ W1, ushort* __restrict__ w1sw)
{
  int t = blockIdx.x*blockDim.x + threadIdx.x;
  if (t >= 2560) return;
  int l = t & 63, nk = t >> 6;
  int nt = nk/5, ks = nk - nt*5;
  int ncol = nt*16 + (l&15);
  int kb = ks*32 + (l>>4)*8;
  union { ushort u[8]; uint4 q; } v;
  #pragma unroll
  for (int j = 0; j < 8; ++j) {
    int k = kb + j;
    float f = (k < 144) ? W1[k*128 + ncol] : 0.f;
    v.u[j] = f2bf(f);
  }
  ((uint4*)w1sw)[t] = v.q;
}

// ---------------- edge MLP via MFMA: wave per 16-edge tile ----------------
// ef[16][160]bf16 @ W1p[160][128]bf16 -> relu(+b1) -> @W2[128][2] -> +b2 -> log_softmax
__global__ __launch_bounds__(256) void edge_mlp_mfma(
    const ushort* __restrict__ h3b, const ushort* __restrict__ attrb,
    const int* __restrict__ src, const int* __restrict__ dst,
    const ushort* __restrict__ w1sw, const float* __restrict__ b1,
    const float* __restrict__ W2, const float* __restrict__ b2,
    float* __restrict__ out, int E)
{
  __shared__ uint4 W1s[2560];            // 40 KB: 40 frags x 64 lanes x 16B
  for (int i = threadIdx.x; i < 2560; i += 256) W1s[i] = ((const uint4*)w1sw)[i];
  __syncthreads();
  const bf16x8* Bf = (const bf16x8*)W1s;

  const int lane = threadIdx.x & 63;
  const int quad = lane >> 4, l15 = lane & 15;

  float w2a[8], w2b[8], bia[8];
  #pragma unroll
  for (int nt = 0; nt < 8; ++nt) {
    w2a[nt] = W2[(nt*16 + l15)*2 + 0];
    w2b[nt] = W2[(nt*16 + l15)*2 + 1];
    bia[nt] = b1[nt*16 + l15];
  }
  const float bb0 = b2[0], bb1 = b2[1];

  const int wid = (blockIdx.x*256 + threadIdx.x) >> 6;
  const int nw  = gridDim.x*4;
  const int nT  = (E + 15) >> 4;

  for (int t = wid; t < nT; t += nw) {
    const int tb = t*16;
    int e = tb + l15; if (e >= E) e = E - 1;
    const int s = src[e], d = dst[e];

    bf16x8 a0 = *(const bf16x8*)(h3b + (size_t)s*64 + quad*8);
    bf16x8 a1 = *(const bf16x8*)(h3b + (size_t)s*64 + 32 + quad*8);
    bf16x8 a2 = *(const bf16x8*)(h3b + (size_t)d*64 + quad*8);
    bf16x8 a3 = *(const bf16x8*)(h3b + (size_t)d*64 + 32 + quad*8);
    bf16x8 a4 = {};
    if (quad < 2) a4 = *(const bf16x8*)(attrb + (size_t)e*16 + quad*8);

    f32x4 acc[8];
    #pragma unroll
    for (int nt = 0; nt < 8; ++nt) acc[nt] = (f32x4){0.f,0.f,0.f,0.f};

    #pragma unroll
    for (int nt = 0; nt < 8; ++nt) {
      acc[nt] = __builtin_amdgcn_mfma_f32_16x16x32_bf16(a0, Bf[(nt*5+0)*64 + lane], acc[nt], 0,0,0);
      acc[nt] = __builtin_amdgcn_mfma_f32_16x16x32_bf16(a1, Bf[(nt*5+1)*64 + lane], acc[nt], 0,0,0);
      acc[nt] = __builtin_amdgcn_mfma_f32_16x16x32_bf16(a2, Bf[(nt*5+2)*64 + lane], acc[nt], 0,0,0);
      acc[nt] = __builtin_amdgcn_mfma_f32_16x16x32_bf16(a3, Bf[(nt*5+3)*64 + lane], acc[nt], 0,0,0);
      acc[nt] = __builtin_amdgcn_mfma_f32_16x16x32_bf16(a4, Bf[(nt*5+4)*64 + lane], acc[nt], 0,0,0);
    }

    // epilogue: C row = quad*4+r (edge in tile), col = nt*16+l15 (hidden)
    #pragma unroll
    for (int r = 0; r < 4; ++r) {
      float p0 = 0.f, p1 = 0.f;
      #pragma unroll
      for (int nt = 0; nt < 8; ++nt) {
        float hv = fmaxf(acc[nt][r] + bia[nt], 0.f);
        p0 = fmaf(hv, w2a[nt], p0);
        p1 = fmaf(hv, w2b[nt], p1);
      }
      #pragma unroll
      for (int off = 1; off < 16; off <<= 1) {
        p0 += __shfl_xor(p0, off, 64);
        p1 += __shfl_xor(p1, off, 64);
      }
      if (l15 == 0) {
        int eo = tb + quad*4 + r;
        if (eo < E) {
          p0 += bb0; p1 += bb1;
          float mm = fmaxf(p0, p1);
          float ls = mm + __logf(__expf(p0-mm) + __expf(p1-mm));
          ((float2*)out)[eo] = make_float2(p0 - ls, p1 - ls);
        }
      }
    }
  }
}

extern "C" void kernel_launch(void* const* d_in, const int* in_sizes, int n_in,
                              void* d_out, int out_size, void* d_ws, size_t ws_size,
                              hipStream_t stream) {
  const float* x      = (const float*)d_in[0];
  const int*   ei     = (const int*)d_in[1];
  const float* attr   = (const float*)d_in[2];
  const float* W1     = (const float*)d_in[3];
  const float* a_src1 = (const float*)d_in[4];
  const float* a_dst1 = (const float*)d_in[5];
  const float* b1     = (const float*)d_in[6];
  const float* W2     = (const float*)d_in[7];
  const float* a_src2 = (const float*)d_in[8];
  const float* a_dst2 = (const float*)d_in[9];
  const float* b2     = (const float*)d_in[10];
  const float* linW   = (const float*)d_in[11];
  const float* linb   = (const float*)d_in[12];
  const float* mW1    = (const float*)d_in[13];
  const float* mb1    = (const float*)d_in[14];
  const float* mW2    = (const float*)d_in[15];
  const float* mb2    = (const float*)d_in[16];
  float* out = (float*)d_out;

  int N = in_sizes[0] / 128;
  int E = in_sizes[1] / 2;
  const int* src = ei;
  const int* dst = ei + E;

  char* ws = (char*)d_ws;
  float*    bufA   = (float*)(ws);                 // 25.6 MB: xW1 / xW2
  float*    bufH   = (float*)(ws + 25600000);      // 25.6 MB: h1 / h2
  int*      csr    = (int*)  (ws + 51200000);      // 6.4 MB (dead after agg2)
  float*    alS1   = (float*)(ws + 57600000);
  float*    alD1   = (float*)(ws + 60800000);
  int*      rowptr = (int*)  (ws + 64000000);
  int*      degcur = (int*)  (ws + 64400064);
  int*      part   = (int*)  (ws + 64800064);
  ushort*   w1sw   = (ushort*)(ws + 64900096);     // 40 KB swizzled W1
  float*    alS2   = (float*)(ws + 57600000);      // alias dead layer-1 logits
  float*    alD2   = (float*)(ws + 58000000);
  // late-phase aliases (after agg2 / final gemm):
  ushort*   h3b    = (ushort*)(ws + 51200000);     // 12.8 MB over dead csr+alS2
  ushort*   attrb  = (ushort*)(ws);                // 51.2 MB over dead bufA+bufH

  int gN4 = (N + 3) / 4;
  int gNH = (N*8 + 255) / 256;
  int gN  = (N + 255) / 256;
  int gE  = (E + 255) / 256;
  int nChunk = (N + 1023) / 1024;

  // ---- CSR build ----
  hipMemsetAsync(degcur, 0, (size_t)N*sizeof(int), stream);
  hist_kernel<<<gE, 256, 0, stream>>>(dst, degcur, E);
  scan_p1<<<nChunk, 256, 0, stream>>>(degcur, part, N);
  scan_p2<<<1, 64, 0, stream>>>(part, rowptr, nChunk, N);
  scan_p3<<<nChunk, 256, 0, stream>>>(degcur, part, rowptr, N);
  copy_int<<<gN, 256, 0, stream>>>(rowptr, degcur, N);
  scatter_kernel<<<gE, 256, 0, stream>>>(src, dst, degcur, csr, E);
  w1_swizzle<<<10, 256, 0, stream>>>(mW1, w1sw);

  // ---- layer 1 ----
  gemm_n64<<<gN4, 256, 0, stream>>>(x, W1, nullptr, bufA, nullptr, N, 128);
  al_init1<<<gNH, 256, 0, stream>>>(bufA, a_src1, a_dst1, alS1, alD1, N);
  agg1<<<gN4, 256, 0, stream>>>(bufA, alS1, alD1, rowptr, csr, b1, bufH, N);
  // ---- layer 2 ----
  gemm_n64<<<gN4, 256, 0, stream>>>(bufH, W2, nullptr, bufA, nullptr, N, 64);
  al_init2<<<gN, 256, 0, stream>>>(bufA, a_src2, a_dst2, alS2, alD2, N);
  agg2<<<gN4, 256, 0, stream>>>(bufA, alS2, alD2, rowptr, csr, b2, bufH, N);
  // ---- linear -> h3 in bf16 (csr/alS2/rowptr now dead) ----
  gemm_n64<<<gN4, 256, 0, stream>>>(bufH, linW, linb, nullptr, h3b, N, 64);
  // ---- attr -> bf16 (bufA+bufH now dead) ----
  attr2bf<<<(E*4 + 255)/256, 256, 0, stream>>>(attr, attrb, E*4);
  // ---- fused edge MLP ----
  edge_mlp_mfma<<<1024, 256, 0, stream>>>(h3b, attrb, src, dst, w1sw, mb1, mW2, mb2, out, E);
}